// Round 2
// baseline (431.476 us; speedup 1.0000x reference)
//
#include <hip/hip_runtime.h>

// Batched Fast Walsh-Hadamard Transform (Sylvester ordering), N=4096, fp32.
// One wave (64 lanes) per row. Each lane holds 64 floats.
//   Phase 1: butterfly stages on element bits 0-5 (h=1..32)  -> register index
//   LDS 64x64 transpose (XOR-swizzled, conflict-free)
//   Phase 2: butterfly stages on element bits 6-11 (h=64..2048) -> register index
// Stage order matches the reference exactly -> bit-exact arithmetic DAG.

#define WHT_N 4096

__global__ __launch_bounds__(64) void fwht4096_kernel(const float* __restrict__ in,
                                                      float* __restrict__ out) {
    __shared__ float lds[WHT_N];  // 16 KiB per 1-wave block

    const int l = threadIdx.x;                       // lane 0..63
    const long long row = blockIdx.x;
    const float* __restrict__ src = in + row * (long long)WHT_N;
    float* __restrict__ dst = out + row * (long long)WHT_N;

    float x[64];

    // ---- load: x[k] = src[64*l + k]  (16 x dwordx4, 64B per lane) ----
#pragma unroll
    for (int j = 0; j < 16; ++j) {
        const float4 v = *reinterpret_cast<const float4*>(src + 64 * l + 4 * j);
        x[4 * j + 0] = v.x;
        x[4 * j + 1] = v.y;
        x[4 * j + 2] = v.z;
        x[4 * j + 3] = v.w;
    }

    // ---- phase 1: element bits 0..5 == register bits (h = 1,2,4,8,16,32) ----
#pragma unroll
    for (int s = 0; s < 6; ++s) {
        const int h = 1 << s;
#pragma unroll
        for (int k0 = 0; k0 < 64; k0 += 2 * (1 << s)) {
#pragma unroll
            for (int m = 0; m < (1 << s); ++m) {
                const float a = x[k0 + m];
                const float b = x[k0 + m + h];
                x[k0 + m] = a + b;
                x[k0 + m + h] = a - b;
            }
        }
    }

    // ---- transpose via LDS, swizzled: addr(i) = i ^ (((i>>6)&7)<<2) ----
    // write: element i = 64*l + 4*j + m  -> addr = 64*l + 4*(j ^ (l&7)) + m (b128)
#pragma unroll
    for (int j = 0; j < 16; ++j) {
        const int a = 64 * l + 4 * (j ^ (l & 7));
        float4 v;
        v.x = x[4 * j + 0];
        v.y = x[4 * j + 1];
        v.z = x[4 * j + 2];
        v.w = x[4 * j + 3];
        *reinterpret_cast<float4*>(&lds[a]) = v;
    }
    __syncthreads();  // 1-wave block: orders ds_write -> ds_read (lgkmcnt)

    // read: element i = l + 64*k -> addr = 64*k + (l ^ ((k&7)<<2))
#pragma unroll
    for (int k = 0; k < 64; ++k) {
        x[k] = lds[64 * k + (l ^ ((k & 7) << 2))];
    }

    // ---- phase 2: element bits 6..11 == register bits (h_elem = 64..2048) ----
#pragma unroll
    for (int s = 0; s < 6; ++s) {
        const int h = 1 << s;
#pragma unroll
        for (int k0 = 0; k0 < 64; k0 += 2 * (1 << s)) {
#pragma unroll
            for (int m = 0; m < (1 << s); ++m) {
                const float a = x[k0 + m];
                const float b = x[k0 + m + h];
                x[k0 + m] = a + b;
                x[k0 + m + h] = a - b;
            }
        }
    }

    // ---- store: out[l + 64*k] = x[k]  (coalesced 256B per instruction) ----
#pragma unroll
    for (int k = 0; k < 64; ++k) {
        dst[l + 64 * k] = x[k];
    }
}

extern "C" void kernel_launch(void* const* d_in, const int* in_sizes, int n_in,
                              void* d_out, int out_size, void* d_ws, size_t ws_size,
                              hipStream_t stream) {
    const float* x = (const float*)d_in[0];
    float* out = (float*)d_out;
    const int rows = in_sizes[0] / WHT_N;  // 16384

    dim3 grid(rows);
    dim3 block(64);
    fwht4096_kernel<<<grid, block, 0, stream>>>(x, out);
}

// Round 4
// 430.104 us; speedup vs baseline: 1.0032x; 1.0032x over previous
//
#include <hip/hip_runtime.h>

// Batched FWHT (Sylvester), N=4096, fp32, 16384 rows.
// One 256-thread block per row; 16 floats per thread.
//
// Element e (12 bits). Thread t (8 bits), reg r (4 bits).
// Layouts (which element bits live in the register index):
//   L0 (load/store): r = e{11,10,1,0}, t = e{9..2}   -> stages h=1,2 then (at end) h=1024,2048
//   L1:              r = e{5..2},  t = (e9 e8 e7 e6 e11 e10 e1 e0) -> stages h=4..32
//   L2:              r = e{9..6},  t = (e5 e4 e3 e2 e11 e10 e1 e0) -> stages h=64..512
// Three LDS exchanges (E1: L0->L1, E2: L1->L2, E3: L2->L0), all through one
// 16 KiB buffer addressed by swizzled element index:
//   sigma(e) = e ^ (((e>>6)&7)<<2) ^ (((e>>10)&3)<<3)
// -> every write/read pattern is <=2-way bank aliased (free), and sigma folds
// to one v_xor per access. Stage order is globally ascending h (bit 0..11),
// identical pairing/sign to the reference -> bit-exact (absmax 0).
//
// launch_bounds (256,4): cap 64 VGPR. (256,8)'s 32-VGPR cap would spill
// (16 data regs + 16 in-flight load regs + bases > 32). Usage <=64 still
// allows 8 waves/SIMD (occupancy step at 64) and 8 blocks/CU LDS-wise.

#define WHT_N 4096

#define BFLY(d)                                          \
    _Pragma("unroll")                                    \
    for (int r = 0; r < 16; ++r) {                       \
        if ((r & (d)) == 0) {                            \
            const float a_ = x[r], b_ = x[r ^ (d)];      \
            x[r] = a_ + b_;                              \
            x[r ^ (d)] = a_ - b_;                        \
        }                                                \
    }

__global__ __launch_bounds__(256, 4) void fwht4096_kernel(const float* __restrict__ in,
                                                          float* __restrict__ out) {
    __shared__ float lds[WHT_N];  // 16 KiB

    const int t = threadIdx.x;  // 0..255
    const long long row = blockIdx.x;
    const float* __restrict__ src = in + row * (long long)WHT_N;
    float* __restrict__ dst = out + row * (long long)WHT_N;

    float x[16];

    // ---- L0 load: x[4i+m] = src[(i<<10) | (t<<2) | m] ----
    // per instr: 256 threads x 16B contiguous = 4 KiB, perfectly coalesced
#pragma unroll
    for (int i = 0; i < 4; ++i) {
        const float4 v = *reinterpret_cast<const float4*>(src + (i << 10) + (t << 2));
        x[4 * i + 0] = v.x;
        x[4 * i + 1] = v.y;
        x[4 * i + 2] = v.z;
        x[4 * i + 3] = v.w;
    }

    // ---- stages: element bits 0,1 (h=1,2) -> reg bits 0,1 ----
    BFLY(1)
    BFLY(2)

    // ---- E1 write (L0): addr = tb ^ (i<<10) ^ (i<<3), float4 ----
    const int tb = (t << 2) ^ (((t >> 4) & 7) << 2);
#pragma unroll
    for (int i = 0; i < 4; ++i) {
        const int a = tb ^ (i << 10) ^ (i << 3);
        *reinterpret_cast<float4*>(&lds[a]) =
            make_float4(x[4 * i + 0], x[4 * i + 1], x[4 * i + 2], x[4 * i + 3]);
    }
    __syncthreads();

    // ---- E1 read (L1): addr = B1 ^ (r<<2) ----
    // sbase1 = e11,10<-t{3:2} | e9..6<-t{7:4} | e1,0<-t{1:0}; sigma folded into bits 4:2
    const int B1 = (((((t >> 2) & 3) << 10) | ((t >> 4) << 6) | (t & 3))) ^
                   (((((t >> 4) & 7) ^ (((t >> 2) & 3) << 1))) << 2);
#pragma unroll
    for (int r = 0; r < 16; ++r) x[r] = lds[B1 ^ (r << 2)];

    // ---- stages: element bits 2..5 (h=4,8,16,32) -> reg bits 0..3 ----
    BFLY(1)
    BFLY(2)
    BFLY(4)
    BFLY(8)

    __syncthreads();
    // ---- E2 write (L1): same addressing as E1 read ----
#pragma unroll
    for (int r = 0; r < 16; ++r) lds[B1 ^ (r << 2)] = x[r];
    __syncthreads();

    // ---- E2 read (L2): addr = B2 ^ ((r<<6) | ((r&7)<<2)) ----
    // base2 = e11,10<-t{3:2} | e5..2<-t{7:4} | e1,0<-t{1:0}; sigma's (e>>10)&3 term folded
    const int B2 = (((((t >> 2) & 3) << 10) | ((t >> 4) << 2) | (t & 3))) ^
                   ((((t >> 2) & 3)) << 3);
#pragma unroll
    for (int r = 0; r < 16; ++r) x[r] = lds[B2 ^ ((r << 6) | ((r & 7) << 2))];

    // ---- stages: element bits 6..9 (h=64,128,256,512) -> reg bits 0..3 ----
    BFLY(1)
    BFLY(2)
    BFLY(4)
    BFLY(8)

    __syncthreads();
    // ---- E3 write (L2): same addressing as E2 read ----
#pragma unroll
    for (int r = 0; r < 16; ++r) lds[B2 ^ ((r << 6) | ((r & 7) << 2))] = x[r];
    __syncthreads();

    // ---- E3 read (L0): float4, same addressing as E1 write ----
#pragma unroll
    for (int i = 0; i < 4; ++i) {
        const float4 v = *reinterpret_cast<const float4*>(&lds[tb ^ (i << 10) ^ (i << 3)]);
        x[4 * i + 0] = v.x;
        x[4 * i + 1] = v.y;
        x[4 * i + 2] = v.z;
        x[4 * i + 3] = v.w;
    }

    // ---- stages: element bits 10,11 (h=1024,2048) -> reg bits 2,3 ----
    BFLY(4)
    BFLY(8)

    // ---- L0 store: coalesced float4 ----
#pragma unroll
    for (int i = 0; i < 4; ++i) {
        *reinterpret_cast<float4*>(dst + (i << 10) + (t << 2)) =
            make_float4(x[4 * i + 0], x[4 * i + 1], x[4 * i + 2], x[4 * i + 3]);
    }
}

extern "C" void kernel_launch(void* const* d_in, const int* in_sizes, int n_in,
                              void* d_out, int out_size, void* d_ws, size_t ws_size,
                              hipStream_t stream) {
    const float* x = (const float*)d_in[0];
    float* out = (float*)d_out;
    const int rows = in_sizes[0] / WHT_N;  // 16384

    fwht4096_kernel<<<dim3(rows), dim3(256), 0, stream>>>(x, out);
}